// Round 1
// baseline (1932.975 us; speedup 1.0000x reference)
//
#include <hip/hip_runtime.h>
#include <math.h>

// ---------------------------------------------------------------------------
// SelfposOnlyVec: BN->Lin->ReLU chain (width 16) with 2 residual blocks,
// concat with 8-entry embedding, classify to 64 outputs. N = 2,000,000.
//
// Training-mode BN => batch stats over intermediates => multi-pass:
//   stats0(pos) -> fold0 -> stats1(h) -> fold1 -> ... -> stats4(y3) -> fold4
//   -> table (emb@wc_e^T+bc precomputed per part id) -> final (512MB write)
// Intermediates are recomputed from pos (16MB) instead of spilled (128MB).
// BN is folded into the following linear's weights by tiny 1-block kernels.
//
// R1 change: k_final rewritten as a two-phase LDS tile.
//   Old: one thread per row wrote 64 floats at 256-B lane stride -> every
//   store instruction touched 64 distinct cache lines (request-rate bound,
//   ~0.25 TB/s effective). Also per-lane t2 gathers.
//   New: phase 1 computes h3 per thread -> LDS; phase 2 maps 16 threads per
//   row (chunk = tid&15) so a wave stores 1 KB contiguous; t2 staged in LDS;
//   classifier weights held in registers (float4 w4[16] per thread).
// ---------------------------------------------------------------------------

#define WG 256
#define GRID_STATS 1024
#define GRID_FINAL 2048

// ws layout (floats)
#define PARTIALS_OFF 0                    // GRID_STATS*32 floats
#define PARAMS_OFF   (GRID_STATS * 32)    // folded params block
// offsets relative to params base P
#define PW1 0      // [16][2]
#define PB1 32     // [16]
#define PW2 48     // [16][16]
#define PB2 304
#define PW3 320
#define PB3 576
#define PW4 592
#define PB4 848
#define PW5 864
#define PB5 1120
#define PT2 1136   // table2 [8][64]
// params end at 1648 floats; total ws use = (32768+1648)*4 ~ 138 KB

__device__ __forceinline__ void lin_relu16(const float* __restrict__ W,
                                           const float* __restrict__ B,
                                           const float x[16], float y[16]) {
  #pragma unroll
  for (int o = 0; o < 16; ++o) {
    float acc = B[o];
    #pragma unroll
    for (int i = 0; i < 16; ++i) acc = fmaf(W[o * 16 + i], x[i], acc);
    y[o] = fmaxf(acc, 0.f);
  }
}

// DEPTH: 0=raw pos (padded to 16), 1=h, 2=y1, 3=h2, 4=y3, 5=h3
template <int DEPTH>
__device__ __forceinline__ void forward_row(const float* __restrict__ P,
                                            float x0, float x1, float v[16]) {
  if (DEPTH == 0) {
    v[0] = x0; v[1] = x1;
    #pragma unroll
    for (int i = 2; i < 16; ++i) v[i] = 0.f;
    return;
  }
  float h[16];
  #pragma unroll
  for (int o = 0; o < 16; ++o)
    h[o] = fmaxf(fmaf(P[PW1 + 2 * o], x0, fmaf(P[PW1 + 2 * o + 1], x1, P[PB1 + o])), 0.f);
  if (DEPTH == 1) {
    #pragma unroll
    for (int i = 0; i < 16; ++i) v[i] = h[i];
    return;
  }
  float y[16];
  lin_relu16(P + PW2, P + PB2, h, y);      // y1
  if (DEPTH == 2) {
    #pragma unroll
    for (int i = 0; i < 16; ++i) v[i] = y[i];
    return;
  }
  float z[16];
  lin_relu16(P + PW3, P + PB3, y, z);      // y2
  #pragma unroll
  for (int o = 0; o < 16; ++o) h[o] += z[o];  // h2 = h + y2
  if (DEPTH == 3) {
    #pragma unroll
    for (int i = 0; i < 16; ++i) v[i] = h[i];
    return;
  }
  lin_relu16(P + PW4, P + PB4, h, y);      // y3
  if (DEPTH == 4) {
    #pragma unroll
    for (int i = 0; i < 16; ++i) v[i] = y[i];
    return;
  }
  lin_relu16(P + PW5, P + PB5, y, z);      // y4
  #pragma unroll
  for (int o = 0; o < 16; ++o) h[o] += z[o];  // h3 = h2 + y4
  #pragma unroll
  for (int i = 0; i < 16; ++i) v[i] = h[i];
}

// Per-pass stats: per-thread sums -> wave shuffle reduce -> LDS -> per-block
// partials[block*32 + c] (c<16: sum, c>=16: sumsq). Deterministic, no atomics.
template <int DEPTH>
__global__ __launch_bounds__(WG) void k_stats(const float* __restrict__ pos, int N,
                                              const float* __restrict__ P,
                                              float* __restrict__ partials) {
  constexpr int NC = (DEPTH == 0) ? 2 : 16;  // raw pos is width-2
  float s[16], q[16];
  #pragma unroll
  for (int c = 0; c < 16; ++c) { s[c] = 0.f; q[c] = 0.f; }
  const float2* pos2 = (const float2*)pos;
  for (int r = blockIdx.x * WG + threadIdx.x; r < N; r += GRID_STATS * WG) {
    float2 p = pos2[r];
    float v[16];
    forward_row<DEPTH>(P, p.x, p.y, v);
    #pragma unroll
    for (int c = 0; c < NC; ++c) { s[c] += v[c]; q[c] = fmaf(v[c], v[c], q[c]); }
  }
  __shared__ float redS[4][16], redQ[4][16];
  int lane = threadIdx.x & 63, wave = threadIdx.x >> 6;
  #pragma unroll
  for (int c = 0; c < 16; ++c) {
    float vs = s[c], vq = q[c];
    #pragma unroll
    for (int m = 1; m < 64; m <<= 1) {
      vs += __shfl_xor(vs, m, 64);
      vq += __shfl_xor(vq, m, 64);
    }
    if (lane == 0) { redS[wave][c] = vs; redQ[wave][c] = vq; }
  }
  __syncthreads();
  if (threadIdx.x < 16) {
    int c = threadIdx.x;
    partials[blockIdx.x * 32 + c]      = redS[0][c] + redS[1][c] + redS[2][c] + redS[3][c];
    partials[blockIdx.x * 32 + 16 + c] = redQ[0][c] + redQ[1][c] + redQ[2][c] + redQ[3][c];
  }
}

// One block: reduce partials -> mean/var -> fold BN into next linear.
// Wf[o][c] = W[o][c]*scale[c]; bf[o] = bias[o] + sum_c W[o][c]*shift[c]
__global__ __launch_bounds__(WG) void k_fold(const float* __restrict__ partials,
                                             const float* __restrict__ gam,
                                             const float* __restrict__ bet,
                                             const float* __restrict__ W,
                                             const float* __restrict__ bias,
                                             int C, int O, float invN,
                                             float* __restrict__ Wf,
                                             float* __restrict__ bf) {
  __shared__ float red[8][32];
  __shared__ float colsum[32];
  __shared__ float scale[16], shift[16];
  int t = threadIdx.x;
  int c = t & 31, grp = t >> 5;
  float acc = 0.f;
  for (int bI = grp; bI < GRID_STATS; bI += 8) acc += partials[bI * 32 + c];
  red[grp][c] = acc;
  __syncthreads();
  if (t < 32) {
    float x = 0.f;
    #pragma unroll
    for (int g2 = 0; g2 < 8; ++g2) x += red[g2][t];
    colsum[t] = x;
  }
  __syncthreads();
  if (t < C) {
    float mean = colsum[t] * invN;
    float var  = colsum[16 + t] * invN - mean * mean;
    float sc   = gam[t] / sqrtf(var + 1e-5f);
    scale[t] = sc;
    shift[t] = bet[t] - mean * sc;
  }
  __syncthreads();
  for (int o = t; o < O; o += WG) {
    float a2 = bias[o];
    for (int cc = 0; cc < C; ++cc) {
      float w = W[o * C + cc];
      Wf[o * C + cc] = w * scale[cc];
      a2 = fmaf(w, shift[cc], a2);
    }
    bf[o] = a2;
  }
}

// table2[p][o] = bc[o] + sum_i emb[p][i] * wc[o][16+i]   (8x64)
__global__ void k_table(const float* __restrict__ emb, const float* __restrict__ wc,
                        const float* __restrict__ bc, float* __restrict__ t2) {
  int t = threadIdx.x;  // 512 threads
  int p = t >> 6, o = t & 63;
  float acc = bc[o];
  #pragma unroll
  for (int i = 0; i < 16; ++i) acc = fmaf(emb[p * 16 + i], wc[o * 32 + 16 + i], acc);
  t2[p * 64 + o] = acc;
}

// Final pass, two-phase per 256-row tile:
//   phase 1: thread t computes h3(row base+t) -> sh[t][0:16], idx -> sidx[t]
//   phase 2: 16 threads per row (chunk = t&15); each computes 4 outputs
//            (o = chunk*4 + 0..3) from sh + register weights + LDS t2 and
//            stores one float4. Lanes 0..15 cover one row's 256 B, a wave
//            stores 1 KB contiguous -> fully coalesced.
__global__ __launch_bounds__(WG) void k_final(const float* __restrict__ pos,
                                              const int* __restrict__ idx,
                                              const float* __restrict__ P,
                                              const float* __restrict__ wc,
                                              float* __restrict__ out, int N) {
  __shared__ float sh[256][20];   // h3 per row; stride 20 floats (80 B, 16B-aligned)
  __shared__ int   sidx[256];
  __shared__ float4 st2[128];     // t2 as float4: [pid][chunk], 8*16

  const int t = threadIdx.x;
  const int chunk = t & 15;
  const int rgrp  = t >> 4;

  // stage t2 (8x64 floats = 128 float4); ordered before phase-2 reads by the
  // in-loop __syncthreads() after phase 1.
  if (t < 128) st2[t] = ((const float4*)(P + PT2))[t];

  // classifier weights for this thread's 4 output columns: w4[i] holds
  // wc[(chunk*4 + 0..3)*32 + i] in .x..w  (64 VGPR, loaded once, L1-hit)
  float4 w4[16];
  #pragma unroll
  for (int i = 0; i < 16; ++i) {
    w4[i].x = wc[(chunk * 4 + 0) * 32 + i];
    w4[i].y = wc[(chunk * 4 + 1) * 32 + i];
    w4[i].z = wc[(chunk * 4 + 2) * 32 + i];
    w4[i].w = wc[(chunk * 4 + 3) * 32 + i];
  }

  const float2* pos2 = (const float2*)pos;

  for (int base = blockIdx.x * WG; base < N; base += gridDim.x * WG) {
    int r = base + t;
    if (r < N) {
      float2 p = pos2[r];
      float h3[16];
      forward_row<5>(P, p.x, p.y, h3);
      float4* row4 = (float4*)&sh[t][0];
      #pragma unroll
      for (int ii = 0; ii < 4; ++ii)
        row4[ii] = make_float4(h3[ii * 4 + 0], h3[ii * 4 + 1],
                               h3[ii * 4 + 2], h3[ii * 4 + 3]);
      sidx[t] = idx[r];
    }
    __syncthreads();

    #pragma unroll
    for (int k = 0; k < 16; ++k) {
      int rb = (k << 4) + rgrp;   // row in tile; lanes 0..15 share rb
      int rg = base + rb;
      if (rg < N) {
        float4 acc = st2[sidx[rb] * 16 + chunk];
        const float4* hrow = (const float4*)&sh[rb][0];
        #pragma unroll
        for (int ii = 0; ii < 4; ++ii) {
          float4 hv = hrow[ii];   // broadcast across the 16 lanes of this row
          acc.x = fmaf(w4[ii * 4 + 0].x, hv.x, acc.x);
          acc.y = fmaf(w4[ii * 4 + 0].y, hv.x, acc.y);
          acc.z = fmaf(w4[ii * 4 + 0].z, hv.x, acc.z);
          acc.w = fmaf(w4[ii * 4 + 0].w, hv.x, acc.w);
          acc.x = fmaf(w4[ii * 4 + 1].x, hv.y, acc.x);
          acc.y = fmaf(w4[ii * 4 + 1].y, hv.y, acc.y);
          acc.z = fmaf(w4[ii * 4 + 1].z, hv.y, acc.z);
          acc.w = fmaf(w4[ii * 4 + 1].w, hv.y, acc.w);
          acc.x = fmaf(w4[ii * 4 + 2].x, hv.z, acc.x);
          acc.y = fmaf(w4[ii * 4 + 2].y, hv.z, acc.y);
          acc.z = fmaf(w4[ii * 4 + 2].z, hv.z, acc.z);
          acc.w = fmaf(w4[ii * 4 + 2].w, hv.z, acc.w);
          acc.x = fmaf(w4[ii * 4 + 3].x, hv.w, acc.x);
          acc.y = fmaf(w4[ii * 4 + 3].y, hv.w, acc.y);
          acc.z = fmaf(w4[ii * 4 + 3].z, hv.w, acc.z);
          acc.w = fmaf(w4[ii * 4 + 3].w, hv.w, acc.w);
        }
        ((float4*)(out + (size_t)rg * 64))[chunk] = acc;
      }
    }
    __syncthreads();
  }
}

extern "C" void kernel_launch(void* const* d_in, const int* in_sizes, int n_in,
                              void* d_out, int out_size, void* d_ws, size_t ws_size,
                              hipStream_t stream) {
  const float* pos = (const float*)d_in[0];
  const int*   idx = (const int*)d_in[1];
  const float* bn_g[5] = {(const float*)d_in[2], (const float*)d_in[4], (const float*)d_in[6],
                          (const float*)d_in[8], (const float*)d_in[10]};
  const float* bn_b[5] = {(const float*)d_in[3], (const float*)d_in[5], (const float*)d_in[7],
                          (const float*)d_in[9], (const float*)d_in[11]};
  const float* w[5] = {(const float*)d_in[12], (const float*)d_in[14], (const float*)d_in[16],
                       (const float*)d_in[18], (const float*)d_in[20]};
  const float* b[5] = {(const float*)d_in[13], (const float*)d_in[15], (const float*)d_in[17],
                       (const float*)d_in[19], (const float*)d_in[21]};
  const float* emb = (const float*)d_in[22];
  const float* wc  = (const float*)d_in[23];
  const float* bc  = (const float*)d_in[24];
  float* out = (float*)d_out;

  int N = in_sizes[0] / 2;
  float invN = 1.0f / (float)N;

  float* ws = (float*)d_ws;
  float* partials = ws + PARTIALS_OFF;
  float* P = ws + PARAMS_OFF;

  // bn0 stats on raw pos, fold into w1
  k_stats<0><<<GRID_STATS, WG, 0, stream>>>(pos, N, P, partials);
  k_fold<<<1, WG, 0, stream>>>(partials, bn_g[0], bn_b[0], w[0], b[0], 2, 16, invN,
                               P + PW1, P + PB1);
  // bn1 stats on h, fold into w2
  k_stats<1><<<GRID_STATS, WG, 0, stream>>>(pos, N, P, partials);
  k_fold<<<1, WG, 0, stream>>>(partials, bn_g[1], bn_b[1], w[1], b[1], 16, 16, invN,
                               P + PW2, P + PB2);
  // bn2 stats on y1, fold into w3
  k_stats<2><<<GRID_STATS, WG, 0, stream>>>(pos, N, P, partials);
  k_fold<<<1, WG, 0, stream>>>(partials, bn_g[2], bn_b[2], w[2], b[2], 16, 16, invN,
                               P + PW3, P + PB3);
  // bn3 stats on h2, fold into w4
  k_stats<3><<<GRID_STATS, WG, 0, stream>>>(pos, N, P, partials);
  k_fold<<<1, WG, 0, stream>>>(partials, bn_g[3], bn_b[3], w[3], b[3], 16, 16, invN,
                               P + PW4, P + PB4);
  // bn4 stats on y3, fold into w5
  k_stats<4><<<GRID_STATS, WG, 0, stream>>>(pos, N, P, partials);
  k_fold<<<1, WG, 0, stream>>>(partials, bn_g[4], bn_b[4], w[4], b[4], 16, 16, invN,
                               P + PW5, P + PB5);
  // embedding-side classifier table
  k_table<<<1, 512, 0, stream>>>(emb, wc, bc, P + PT2);
  // final: recompute chain, two-phase tile, coalesced [N,64] write
  k_final<<<GRID_FINAL, WG, 0, stream>>>(pos, idx, P, wc, out, N);
}